// Round 1
// baseline (184.421 us; speedup 1.0000x reference)
//
#include <hip/hip_runtime.h>
#include <hip/hip_bf16.h>
#include <math.h>

// MMD (InfoVAE RBF kernel), N=8192, D=128, fp32 in, scalar fp32 out.
//
// Round 11: LDS-free, barrier-free mmd_mfma.
//   Rationale (r10 counters): MfmaUtil 25%, HBM 4.4%, bank-conflict 0,
//   dur 54.7us vs 16.7us MFMA floor. The 2-phase LDS staging pays 4
//   syncthreads (vmcnt(0) drains stalling all resident waves) + ~27us of
//   LDS-pipe traffic (128 KB/block) to shuttle data that is L2-resident
//   (Z = 4 MB = one XCD L2; FETCH_SIZE 18.5 MB confirms cache residency).
//   With K=128 there is no steady-state K-loop to pipeline - the staging
//   is pure overhead.
//   Fix: each wave loads its MFMA fragments directly from global/L2
//   (16 B/lane, disjoint lanes, 16 rows x 64 B segments per load),
//   register-double-buffered over the four K=32 slices. No __shared__,
//   no __syncthreads. Norm vectors read from global in the epilogue.
//   Per-wave shuffle reduce + fp64 atomicAdd into 256 spread slots.
//   Address algebra is identical to the r2-r10-verified LDS read stream
//   (staging swizzle c^(r&7) cancels against the read-side XOR; effective
//   global chunk = ks*4+quad), and MFMA/epilogue order is unchanged ->
//   accumulation is bitwise-identical; only the final fp64 reduction
//   order changes (atomic slot split), ~1e-16 relative.
//   Numerics (r3-r6): bf16 MFMA arg noise zero-mean -> ~2e-9 MMD shift;
//   exp2 HW bias cancels in +1+1-2; fp32 partials (<=16); fp64 block/
//   global accumulation. absmax held at 5.96e-8 (threshold 7.15e-8).

#define NN 8192
#define DD 128
#define TZ 16384
#define TILES 128
#define NBLOCKS (TILES * (TILES + 1) / 2)   // 8256

typedef __attribute__((ext_vector_type(8))) short bf16x8;
typedef __attribute__((ext_vector_type(4))) float f32x4;
typedef __attribute__((ext_vector_type(2))) float f32x2;

#if __has_builtin(__builtin_amdgcn_exp2f)
#define EXP2F __builtin_amdgcn_exp2f
#else
#define EXP2F exp2f
#endif

constexpr float LOG2E = 0x1.715476p+0f;
constexpr float S2 = LOG2E / 8192.0f;              // 2*log2e/16384

// ---- ws layout ----
constexpr size_t WS_NORM = 2048;                   // sums: 256 fp64 slots
constexpr size_t WS_Z    = WS_NORM + (size_t)TZ * sizeof(float);

__global__ __launch_bounds__(256) void prep(
    const float* __restrict__ X, const float* __restrict__ Y,
    __hip_bfloat16* __restrict__ Z, float* __restrict__ normZ,
    double* __restrict__ sums) {
  if (blockIdx.x == 0) sums[threadIdx.x] = 0.0;    // 256 slots

  const int row = blockIdx.x * 4 + (threadIdx.x >> 6);
  const int lane = threadIdx.x & 63;
  const float* __restrict__ src =
      (row < NN) ? (X + (size_t)row * DD) : (Y + (size_t)(row - NN) * DD);
  const float2 v = *reinterpret_cast<const float2*>(src + 2 * lane);

  float n = v.x * v.x + v.y * v.y;
  *reinterpret_cast<__hip_bfloat162*>(Z + (size_t)row * DD + 2 * lane) =
      __hip_bfloat162{__float2bfloat16(v.x), __float2bfloat16(v.y)};

#pragma unroll
  for (int o = 32; o > 0; o >>= 1) n += __shfl_down(n, o);
  if (lane == 0) normZ[row] = n * (-LOG2E / 16384.0f);  // pre-scaled
}

__device__ __forceinline__ int tri_start(int i) {
  return i * TILES - (i * (i - 1)) / 2;
}

__global__ __launch_bounds__(256, 3) void mmd_mfma(
    const __hip_bfloat16* __restrict__ Z, const float* __restrict__ normZ,
    double* __restrict__ sums) {
  const int t = blockIdx.x;
  int I = (int)((257.0 - sqrt(257.0 * 257.0 - 8.0 * (double)t)) * 0.5);
  if (I > 127) I = 127;
  if (I < 0) I = 0;
  while (I < 127 && tri_start(I + 1) <= t) ++I;
  while (I > 0 && tri_start(I) > t) --I;
  const int J = I + (t - tri_start(I));

  const int tid = threadIdx.x;
  const int lane = tid & 63, wave = tid >> 6;
  const int wr = wave >> 1, wc = wave & 1;       // 2x2 wave grid over 128x128
  const int lr = lane & 15, quad = lane >> 4;    // MFMA lane decomposition

  // Fragment pointers (verified layout, staging swizzle algebra folded out):
  //   A frag (i, ks): row I*128 + wr*64 + i*16 + lr, bytes ks*64 + quad*16
  //   B frag (j, ks): row J*128 + wc*64 + j*16 + lr, same k offsets.
  const char* Zb = (const char*)Z;
  const char* pA[4];
  const char* pB[4];
#pragma unroll
  for (int i = 0; i < 4; ++i) {
    pA[i] = Zb + (size_t)(I * 128 + wr * 64 + i * 16 + lr) * 256 + quad * 16;
    pB[i] = Zb + (size_t)(J * 128 + wc * 64 + i * 16 + lr) * 256 + quad * 16;
  }

  f32x4 acc[4][4] = {};
  bf16x8 a[2][4], b[2][4];

  // Prologue: issue K-slices 0 and 1 (16 loads in flight).
#pragma unroll
  for (int i = 0; i < 4; ++i) {
    a[0][i] = *reinterpret_cast<const bf16x8*>(pA[i]);
    b[0][i] = *reinterpret_cast<const bf16x8*>(pB[i]);
  }
#pragma unroll
  for (int i = 0; i < 4; ++i) {
    a[1][i] = *reinterpret_cast<const bf16x8*>(pA[i] + 64);
    b[1][i] = *reinterpret_cast<const bf16x8*>(pB[i] + 64);
  }

  // K loop: MFMA slice ks from buffer ks&1, prefetch slice ks+2 into it.
  // Full unroll -> all buffer indices compile-time (no scratch).
#pragma unroll
  for (int ks = 0; ks < 4; ++ks) {
    const int cur = ks & 1;
#pragma unroll
    for (int i = 0; i < 4; ++i)
#pragma unroll
      for (int j = 0; j < 4; ++j)
        acc[i][j] = __builtin_amdgcn_mfma_f32_16x16x32_bf16(
            a[cur][i], b[cur][j], acc[i][j], 0, 0, 0);
    if (ks < 2) {
#pragma unroll
      for (int i = 0; i < 4; ++i) {
        a[cur][i] = *reinterpret_cast<const bf16x8*>(pA[i] + (ks + 2) * 64);
        b[cur][i] = *reinterpret_cast<const bf16x8*>(pB[i] + (ks + 2) * 64);
      }
    }
  }

  // Norms (L2-hot, issued after the MFMA loop when frag regs are dead).
  const float* nzA = normZ + I * 128 + wr * 64;
  const float* nzB = normZ + J * 128 + wc * 64;
  f32x4 ar[4];
  float cb[4];
#pragma unroll
  for (int i = 0; i < 4; ++i)
    ar[i] = *reinterpret_cast<const f32x4*>(nzA + i * 16 + quad * 4);
#pragma unroll
  for (int j = 0; j < 4; ++j) cb[j] = nzB[j * 16 + lr];

  // Epilogue (C/D: col=lane&15, row=quad*4+reg), packed fp32 pairs:
  // k = exp2(acc*S2 + ra + rb), ra/rb pre-scaled by -log2e/16384.
  const f32x2 s2v = {S2, S2};
  f32x2 part01 = {0.f, 0.f}, part23 = {0.f, 0.f};
#pragma unroll
  for (int i = 0; i < 4; ++i) {
    const f32x2 ar01 = {ar[i].x, ar[i].y};
    const f32x2 ar23 = {ar[i].z, ar[i].w};
#pragma unroll
    for (int j = 0; j < 4; ++j) {
      const f32x2 rb2 = {cb[j], cb[j]};
      const f32x2 base01 = ar01 + rb2;
      const f32x2 base23 = ar23 + rb2;
      const f32x2 acc01 = {acc[i][j][0], acc[i][j][1]};
      const f32x2 acc23 = {acc[i][j][2], acc[i][j][3]};
      const f32x2 arg01 = __builtin_elementwise_fma(acc01, s2v, base01);
      const f32x2 arg23 = __builtin_elementwise_fma(acc23, s2v, base23);
      part01 += (f32x2){EXP2F(arg01.x), EXP2F(arg01.y)};
      part23 += (f32x2){EXP2F(arg23.x), EXP2F(arg23.y)};
    }
  }
  const f32x2 ps = part01 + part23;
  double local = (double)(ps.x + ps.y);
  double w = ((I < 64) == (J < 64)) ? 1.0 : -1.0;
  if (I != J) w += w;
  local *= w;

#pragma unroll
  for (int o = 32; o > 0; o >>= 1) local += __shfl_down(local, o);
  if (lane == 0)
    atomicAdd(&sums[((t & 63) << 2) | wave], local);
}

__global__ void finish(const double* __restrict__ s, float* __restrict__ out) {
  double v = s[threadIdx.x] + s[threadIdx.x + 64] + s[threadIdx.x + 128] +
             s[threadIdx.x + 192];
#pragma unroll
  for (int o = 32; o > 0; o >>= 1) v += __shfl_down(v, o);
  if (threadIdx.x == 0)
    out[0] = (float)(v * (1.0 / ((double)NN * (double)NN)));
}

extern "C" void kernel_launch(void* const* d_in, const int* in_sizes, int n_in,
                              void* d_out, int out_size, void* d_ws, size_t ws_size,
                              hipStream_t stream) {
  const float* y_inputs = (const float*)d_in[0];  // "inputs"
  const float* x_true   = (const float*)d_in[1];  // "true_samples"
  float* out = (float*)d_out;

  char* ws = (char*)d_ws;
  double* sums = (double*)ws;                     // 256 fp64 partial slots
  float* normZ = (float*)(ws + WS_NORM);
  __hip_bfloat16* Z = (__hip_bfloat16*)(ws + WS_Z);

  prep<<<TZ / 4, 256, 0, stream>>>(x_true, y_inputs, Z, normZ, sums);
  mmd_mfma<<<NBLOCKS, 256, 0, stream>>>(Z, normZ, sums);
  finish<<<1, 64, 0, stream>>>(sums, out);
}

// Round 2
// 114.309 us; speedup vs baseline: 1.6134x; 1.6134x over previous
//
#include <hip/hip_runtime.h>
#include <hip/hip_bf16.h>
#include <math.h>

// MMD (InfoVAE RBF kernel), N=8192, D=128, fp32 in, scalar fp32 out.
//
// Round 12: K=32-sliced, double-buffered LDS with raw barriers + counted
// vmcnt (m201-style T3/T4), reverting r11's direct-global experiment.
//   r11 post-mortem: direct fragment loads = 16 scattered L1 transactions
//   per wave-load at L2 latency -> MfmaUtil 10%, 131 us. The DMA engine
//   (global_load_lds) was doing real work converting that scatter into
//   linear 1-KB streams. Staging stays.
//   r10 post-mortem: no pipe saturated (matrix 16.7us, LDS ~20us, L2
//   ~15us aggregate vs 54.7us measured) -> the loss is the 2x per-block
//   full vmcnt(0) drain from __syncthreads after staging, convoying all
//   4 resident blocks. Fix: 4 K=32 slices, LDS dbuf 2 x (A 8KB + B 8KB)
//   = 32 KB (same 4 blocks/CU), raw s_barrier + counted vmcnt(4) so the
//   DMA for slice s+2 flies across barriers while slice s computes.
//   Only slice 0 pays DMA latency once per block.
//   Sync hazards handled: {vmcnt;barrier} fused in ONE asm (no ds_read
//   can slip between own-wait and barrier); {lgkmcnt(0);barrier} before
//   re-staging a buffer (all waves' reads done before any DMA overwrite);
//   sched_barrier(0) between lgkm-wait and MFMA cluster (rule #18:
//   "memory" clobber does not order register-only MFMAs).
//   Data/order bitwise identical to r10/r11-passing math:
//   - slice s covers global row bytes [s*64, s*64+64) (s = 2p + ks);
//   - LDS slice panel = 128 rows x 64 B, chunk c' of row r holds global
//     chunk c'^(r&3); fragment read chunk = quad^(lr&3) -> global chunk
//     quad (same operands as r10's verified 8-chunk swizzle);
//   - MFMA order (slice asc, i, j) == r10's (p, ks, i, j);
//   - epilogue math identical to r11 (passed 5.96e-8); norms from global.
//   Staging DMA writes stay linear (lane*16), conflict-free; read-side
//   8 lanes per 16B bank-group with distinct rows = r10's measured-0-
//   conflict density.

#define NN 8192
#define DD 128
#define TZ 16384
#define TILES 128
#define NBLOCKS (TILES * (TILES + 1) / 2)   // 8256

typedef __attribute__((ext_vector_type(8))) short bf16x8;
typedef __attribute__((ext_vector_type(4))) float f32x4;
typedef __attribute__((ext_vector_type(2))) float f32x2;

#if __has_builtin(__builtin_amdgcn_exp2f)
#define EXP2F __builtin_amdgcn_exp2f
#else
#define EXP2F exp2f
#endif

constexpr float LOG2E = 0x1.715476p+0f;
constexpr float S2 = LOG2E / 8192.0f;              // 2*log2e/16384

// ---- ws layout ----
constexpr size_t WS_NORM = 2048;                   // sums: 256 fp64 slots
constexpr size_t WS_Z    = WS_NORM + (size_t)TZ * sizeof(float);

__device__ __forceinline__ void gload_lds16(const void* g, void* l) {
  __builtin_amdgcn_global_load_lds(
      (const __attribute__((address_space(1))) void*)g,
      (__attribute__((address_space(3))) void*)l, 16, 0, 0);
}

__global__ __launch_bounds__(256) void prep(
    const float* __restrict__ X, const float* __restrict__ Y,
    __hip_bfloat16* __restrict__ Z, float* __restrict__ normZ,
    double* __restrict__ sums) {
  if (blockIdx.x == 0) sums[threadIdx.x] = 0.0;    // 256 slots

  const int row = blockIdx.x * 4 + (threadIdx.x >> 6);
  const int lane = threadIdx.x & 63;
  const float* __restrict__ src =
      (row < NN) ? (X + (size_t)row * DD) : (Y + (size_t)(row - NN) * DD);
  const float2 v = *reinterpret_cast<const float2*>(src + 2 * lane);

  float n = v.x * v.x + v.y * v.y;
  *reinterpret_cast<__hip_bfloat162*>(Z + (size_t)row * DD + 2 * lane) =
      __hip_bfloat162{__float2bfloat16(v.x), __float2bfloat16(v.y)};

#pragma unroll
  for (int o = 32; o > 0; o >>= 1) n += __shfl_down(n, o);
  if (lane == 0) normZ[row] = n * (-LOG2E / 16384.0f);  // pre-scaled
}

__device__ __forceinline__ int tri_start(int i) {
  return i * TILES - (i * (i - 1)) / 2;
}

__global__ __launch_bounds__(256, 4) void mmd_mfma(
    const __hip_bfloat16* __restrict__ Z, const float* __restrict__ normZ,
    double* __restrict__ sums) {
  // 2 bufs x (A-slice 8 KB @ +0, B-slice 8 KB @ +8192) = 32 KB (+pad).
  __shared__ alignas(16) char lds[2 * 16384 + 256];

  const int t = blockIdx.x;
  int I = (int)((257.0 - sqrt(257.0 * 257.0 - 8.0 * (double)t)) * 0.5);
  if (I > 127) I = 127;
  if (I < 0) I = 0;
  while (I < 127 && tri_start(I + 1) <= t) ++I;
  while (I > 0 && tri_start(I) > t) --I;
  const int J = I + (t - tri_start(I));

  const int tid = threadIdx.x;
  const int lane = tid & 63, wave = tid >> 6;
  const int wr = wave >> 1, wc = wave & 1;       // 2x2 wave grid over 128x128
  const int lr = lane & 15, quad = lane >> 4;    // MFMA lane decomposition

  // ---- staging geometry ----
  // Issue (wave w, half l in {0,1}): LDS dst = panel + l*4096 + w*1024
  // (wave-uniform), DMA lane-maps +lane*16 -> panel row rdi = 16w + 64l
  // + (lane>>2), chunk c' = lane&3. Source: global chunk g = c'^(rdi&3)
  // of slice s: Zb + (tilerow + rdi)*256 + s*64 + g*16.  (rdi&3 == rd0&3.)
  const char* Zb = (const char*)Z;
  const int rd0 = (wave << 4) + (lane >> 2);           // l=0 panel row
  const int gch = (lane & 3) ^ (rd0 & 3);
  const char* srcA = Zb + ((size_t)(I * 128 + rd0)) * 256 + gch * 16;
  const char* srcB = Zb + ((size_t)(J * 128 + rd0)) * 256 + gch * 16;
  char* ldw = lds + wave * 1024;                       // wave-uniform

#define STAGE(s, buf) do {                                               \
    gload_lds16(srcA + (s) * 64,         ldw + (buf) * 16384);           \
    gload_lds16(srcA + (s) * 64 + 16384, ldw + (buf) * 16384 + 4096);    \
    gload_lds16(srcB + (s) * 64,         ldw + (buf) * 16384 + 8192);    \
    gload_lds16(srcB + (s) * 64 + 16384, ldw + (buf) * 16384 + 12288);   \
  } while (0)

  // ---- fragment read bases (swizzled chunk quad^(lr&3); rows*64 B) ----
  const int csw = (quad ^ (lr & 3)) << 4;
  const char* aRd = lds + (wr * 64 + lr) * 64 + csw;
  const char* bRd = lds + 8192 + (wc * 64 + lr) * 64 + csw;

  bf16x8 a[4], b[4];
  f32x4 acc[4][4] = {};

#define LOADFRAGS(buf) do {                                              \
    _Pragma("unroll")                                                    \
    for (int i = 0; i < 4; ++i) {                                        \
      a[i] = *reinterpret_cast<const bf16x8*>(aRd + (buf) * 16384 + i * 1024); \
      b[i] = *reinterpret_cast<const bf16x8*>(bRd + (buf) * 16384 + i * 1024); \
    }                                                                    \
  } while (0)

#define MFMAS() do {                                                     \
    _Pragma("unroll")                                                    \
    for (int i = 0; i < 4; ++i)                                          \
      _Pragma("unroll")                                                  \
      for (int j = 0; j < 4; ++j)                                        \
        acc[i][j] = __builtin_amdgcn_mfma_f32_16x16x32_bf16(             \
            a[i], b[j], acc[i][j], 0, 0, 0);                             \
  } while (0)

  // Prologue: 8 DMA issues in flight per wave (slices 0,1).
  STAGE(0, 0);
  STAGE(1, 1);

  // ---- slice 0 (buf0) ----
  asm volatile("s_waitcnt vmcnt(4)\n\ts_barrier" ::: "memory");
  LOADFRAGS(0);
  asm volatile("s_waitcnt lgkmcnt(0)\n\ts_barrier" ::: "memory");
  __builtin_amdgcn_sched_barrier(0);
  STAGE(2, 0);                       // safe: all waves done reading buf0
  __builtin_amdgcn_sched_barrier(0);
  MFMAS();

  // ---- slice 1 (buf1) ----
  asm volatile("s_waitcnt vmcnt(4)\n\ts_barrier" ::: "memory");
  LOADFRAGS(1);
  asm volatile("s_waitcnt lgkmcnt(0)\n\ts_barrier" ::: "memory");
  __builtin_amdgcn_sched_barrier(0);
  STAGE(3, 1);
  __builtin_amdgcn_sched_barrier(0);
  MFMAS();

  // ---- slice 2 (buf0, no restage) ----
  asm volatile("s_waitcnt vmcnt(4)\n\ts_barrier" ::: "memory");
  LOADFRAGS(0);
  asm volatile("s_waitcnt lgkmcnt(0)" ::: "memory");
  __builtin_amdgcn_sched_barrier(0);
  MFMAS();

  // ---- slice 3 (buf1, no restage) ----
  asm volatile("s_waitcnt vmcnt(0)\n\ts_barrier" ::: "memory");
  LOADFRAGS(1);
  asm volatile("s_waitcnt lgkmcnt(0)" ::: "memory");
  __builtin_amdgcn_sched_barrier(0);
  MFMAS();

#undef STAGE
#undef LOADFRAGS
#undef MFMAS

  // Norms (L2-hot, loaded after the MFMA pipeline).
  const float* nzA = normZ + I * 128 + wr * 64;
  const float* nzB = normZ + J * 128 + wc * 64;
  f32x4 ar[4];
  float cb[4];
#pragma unroll
  for (int i = 0; i < 4; ++i)
    ar[i] = *reinterpret_cast<const f32x4*>(nzA + i * 16 + quad * 4);
#pragma unroll
  for (int j = 0; j < 4; ++j) cb[j] = nzB[j * 16 + lr];

  // Epilogue (C/D: col=lane&15, row=quad*4+reg), packed fp32 pairs:
  // k = exp2(acc*S2 + ra + rb), ra/rb pre-scaled by -log2e/16384.
  const f32x2 s2v = {S2, S2};
  f32x2 part01 = {0.f, 0.f}, part23 = {0.f, 0.f};
#pragma unroll
  for (int i = 0; i < 4; ++i) {
    const f32x2 ar01 = {ar[i].x, ar[i].y};
    const f32x2 ar23 = {ar[i].z, ar[i].w};
#pragma unroll
    for (int j = 0; j < 4; ++j) {
      const f32x2 rb2 = {cb[j], cb[j]};
      const f32x2 base01 = ar01 + rb2;
      const f32x2 base23 = ar23 + rb2;
      const f32x2 acc01 = {acc[i][j][0], acc[i][j][1]};
      const f32x2 acc23 = {acc[i][j][2], acc[i][j][3]};
      const f32x2 arg01 = __builtin_elementwise_fma(acc01, s2v, base01);
      const f32x2 arg23 = __builtin_elementwise_fma(acc23, s2v, base23);
      part01 += (f32x2){EXP2F(arg01.x), EXP2F(arg01.y)};
      part23 += (f32x2){EXP2F(arg23.x), EXP2F(arg23.y)};
    }
  }
  const f32x2 ps = part01 + part23;
  double local = (double)(ps.x + ps.y);
  double w = ((I < 64) == (J < 64)) ? 1.0 : -1.0;
  if (I != J) w += w;
  local *= w;

#pragma unroll
  for (int o = 32; o > 0; o >>= 1) local += __shfl_down(local, o);
  if (lane == 0)
    atomicAdd(&sums[((t & 63) << 2) | wave], local);
}

__global__ void finish(const double* __restrict__ s, float* __restrict__ out) {
  double v = s[threadIdx.x] + s[threadIdx.x + 64] + s[threadIdx.x + 128] +
             s[threadIdx.x + 192];
#pragma unroll
  for (int o = 32; o > 0; o >>= 1) v += __shfl_down(v, o);
  if (threadIdx.x == 0)
    out[0] = (float)(v * (1.0 / ((double)NN * (double)NN)));
}

extern "C" void kernel_launch(void* const* d_in, const int* in_sizes, int n_in,
                              void* d_out, int out_size, void* d_ws, size_t ws_size,
                              hipStream_t stream) {
  const float* y_inputs = (const float*)d_in[0];  // "inputs"
  const float* x_true   = (const float*)d_in[1];  // "true_samples"
  float* out = (float*)d_out;

  char* ws = (char*)d_ws;
  double* sums = (double*)ws;                     // 256 fp64 partial slots
  float* normZ = (float*)(ws + WS_NORM);
  __hip_bfloat16* Z = (__hip_bfloat16*)(ws + WS_Z);

  prep<<<TZ / 4, 256, 0, stream>>>(x_true, y_inputs, Z, normZ, sums);
  mmd_mfma<<<NBLOCKS, 256, 0, stream>>>(Z, normZ, sums);
  finish<<<1, 64, 0, stream>>>(sums, out);
}